// Round 14
// baseline (169.799 us; speedup 1.0000x reference)
//
#include <hip/hip_runtime.h>
#include <hip/hip_bf16.h>

// Problem constants (B,N,D,H from reference)
#define Bc 64
#define Nc 512
#define Dc 1024
#define Hc 2048
#define Mc (Bc * Nc)          // 32768 rows

// GEMM tiling: 256x256 tile, BK=64, 4 waves (2M x 2N wave grid, 128x128 per
// wave), double-buffered LDS. Bigger wave tile cuts LDS-read demand 33%:
// 128 ds_read_b128 per CU per K-tile (2048 cy) < MFMA demand (2483 cy).
#define BM 256
#define BH 256
#define BK 64
#define KTILES (Dc / BK)      // 16
#define MTILES (Mc / BM)      // 128
#define HTILES (Hc / BH)      // 8
#define NSLICE (HTILES * 2)   // 16 score slices (ht x wave-column)

typedef __attribute__((ext_vector_type(8))) short bf16x8;
typedef __attribute__((ext_vector_type(4))) float f32x4;

__device__ __forceinline__ unsigned short f2bf(float f) {
    unsigned u = __float_as_uint(f);
    u += 0x7FFFu + ((u >> 16) & 1u);   // RNE
    return (unsigned short)(u >> 16);
}

__device__ __forceinline__ void stage16(const void* g, void* l) {
    __builtin_amdgcn_global_load_lds(
        (const __attribute__((address_space(1))) unsigned int*)g,
        (__attribute__((address_space(3))) unsigned int*)l,
        16, 0, 0);
}

// ------- Kernel A: fused {cast x + energy (2 rows/wave)} | {cast W1} --------
__global__ void __launch_bounds__(256) cast_fused(
    const float* __restrict__ x, const float* __restrict__ w1,
    unsigned short* __restrict__ xb, unsigned short* __restrict__ w1b,
    float* __restrict__ energy)
{
    const int tid = threadIdx.x;
    if (blockIdx.x < Mc / 8) {
        const int row0 = blockIdx.x * 8 + (tid >> 6) * 2;
        const int lane = tid & 63;
        const float4* s0 = (const float4*)(x + (size_t)row0 * Dc);
        const float4* s1 = (const float4*)(x + (size_t)(row0 + 1) * Dc);
        ushort4* d0 = (ushort4*)(xb + (size_t)row0 * Dc);
        ushort4* d1 = (ushort4*)(xb + (size_t)(row0 + 1) * Dc);
        float4 v0[4], v1[4];
        #pragma unroll
        for (int j = 0; j < 4; ++j) v0[j] = s0[lane + j * 64];
        #pragma unroll
        for (int j = 0; j < 4; ++j) v1[j] = s1[lane + j * 64];
        float a = 0.0f, bsum = 0.0f;
        #pragma unroll
        for (int j = 0; j < 4; ++j) {
            ushort4 o;
            o.x = f2bf(v0[j].x); o.y = f2bf(v0[j].y);
            o.z = f2bf(v0[j].z); o.w = f2bf(v0[j].w);
            d0[lane + j * 64] = o;
            a += v0[j].x * v0[j].x + v0[j].y * v0[j].y +
                 v0[j].z * v0[j].z + v0[j].w * v0[j].w;
        }
        #pragma unroll
        for (int j = 0; j < 4; ++j) {
            ushort4 o;
            o.x = f2bf(v1[j].x); o.y = f2bf(v1[j].y);
            o.z = f2bf(v1[j].z); o.w = f2bf(v1[j].w);
            d1[lane + j * 64] = o;
            bsum += v1[j].x * v1[j].x + v1[j].y * v1[j].y +
                    v1[j].z * v1[j].z + v1[j].w * v1[j].w;
        }
        #pragma unroll
        for (int m = 1; m < 64; m <<= 1) {
            a    += __shfl_xor(a, m);
            bsum += __shfl_xor(bsum, m);
        }
        if (lane == 0) {
            energy[row0]     = 1.0f / (1.0f + expf(-a));
            energy[row0 + 1] = 1.0f / (1.0f + expf(-bsum));
        }
    } else {
        const size_t i = (size_t)(blockIdx.x - Mc / 8) * 256 + tid; // x4 elems
        const float4 v = ((const float4*)w1)[i];
        ushort4 o;
        o.x = f2bf(v.x); o.y = f2bf(v.y); o.z = f2bf(v.z); o.w = f2bf(v.w);
        ((ushort4*)w1b)[i] = o;
    }
}

// ---------------- Kernel C: fused bf16 GEMM + relu + W2-reduce --------------
// 256x256 tile per block, 4 waves (128x128 per wave), dbuf LDS, prefetch-1
// staging, software-pipelined A-row-pair reads. No setprio (R12 lesson).
// Zero-fills a disjoint 64KB slice of the filter via idle store pipe.
// score_part[(ht*2 + wc)*Mc + row] = sum over slice's 128 h of
//     relu(x.W1[h] + b1[h]) * W2[h]
__global__ void __launch_bounds__(256, 1) fused_gemm_score(
    const unsigned short* __restrict__ xb,    // [Mc][Dc] bf16 bits
    const unsigned short* __restrict__ w1b,   // [Hc][Dc] bf16 bits
    const float* __restrict__ b1,             // [Hc]
    const float* __restrict__ w2,             // [Hc]
    float* __restrict__ score_part,           // [NSLICE][Mc]
    float* __restrict__ zf)                   // filter base to zero, or null
{
    // dynamic LDS: [2 buf][A 32KB | B 32KB] = 128 KB
    extern __shared__ __attribute__((aligned(16))) char lds[];

    const int tid  = threadIdx.x;
    const int lane = tid & 63;
    const int wid  = tid >> 6;                // 0..3
    const int wr   = wid >> 1;                // 0..1  (m half: 128 rows)
    const int wc   = wid & 1;                 // 0..1  (h half: 128 cols)
    const int l15  = lane & 15;
    const int l4   = lane >> 4;               // 0..3

    // bijective XCD swizzle (1024 % 8 == 0): ht fastest within an XCD so the
    // 8 blocks sharing one x-tile run adjacently; W1 (4MB) stays L2-resident.
    const int b  = blockIdx.x;
    const int wg = (b & 7) * (MTILES * HTILES / 8) + (b >> 3);
    const int mt = wg >> 3;                   // 0..127
    const int ht = wg & 7;                    // 0..7
    const int m0 = mt * BM;
    const int h0 = ht * BH;

    // epilogue coefficients prefetch (8 n-frags per wave now)
    float b1v[8], w2v[8];
    #pragma unroll
    for (int n = 0; n < 8; ++n) {
        const int h = h0 + wc * 128 + n * 16 + l15;
        b1v[n] = b1[h];
        w2v[n] = w2[h];
    }

    // staging geometry (rule #21: linear LDS dest + pre-swizzled src col)
    // 256 threads x 16B = 4KB per chunk = 32 rows; 8 chunks per 32KB panel.
    const int srow    = tid >> 3;             // 0..31
    const int scol_sw = ((((tid & 7) * 16) ^ ((srow & 7) << 4)) >> 1); // elems

#define LDSA(bf) (lds + (bf) * 65536)
#define LDSB(bf) (lds + (bf) * 65536 + 32768)

// stage one panel (256 rows x 64 bf16) of K-tile kt: 8 stage16 / thread
#define STG_A(bf, kt) { \
    const unsigned short* _g = xb + (size_t)(m0 + srow) * Dc + (kt) * BK + scol_sw; \
    _Pragma("unroll") for (int c = 0; c < 8; ++c) \
        stage16(_g + (size_t)c * 32 * Dc, LDSA(bf) + c * 4096 + tid * 16); }
#define STG_B(bf, kt) { \
    const unsigned short* _g = w1b + (size_t)(h0 + srow) * Dc + (kt) * BK + scol_sw; \
    _Pragma("unroll") for (int c = 0; c < 8; ++c) \
        stage16(_g + (size_t)c * 32 * Dc, LDSB(bf) + c * 4096 + tid * 16); }

    // swizzled ds_read byte offsets within a 128-byte row
    const int swz   = (l15 & 7) << 4;
    const int offk0 = ((l4 * 16) ^ swz);
    const int offk1 = ((64 + l4 * 16) ^ swz);

// A reads for one row-pair (rows 2p,2p+1 of the wave's 8): 4 x ds_read_b128
#define RD_A2(dst, bf, p) { \
    _Pragma("unroll") for (int r = 0; r < 2; ++r) { \
        dst[r][0] = *(const bf16x8*)(LDSA(bf) + (wr * 128 + ((p)*2+r) * 16 + l15) * 128 + offk0); \
        dst[r][1] = *(const bf16x8*)(LDSA(bf) + (wr * 128 + ((p)*2+r) * 16 + l15) * 128 + offk1); } }
// all 8 B n-frags: 16 x ds_read_b128
#define RD_B8(bf) { \
    _Pragma("unroll") for (int n = 0; n < 8; ++n) { \
        bfr[n][0] = *(const bf16x8*)(LDSB(bf) + (wc * 128 + n * 16 + l15) * 128 + offk0); \
        bfr[n][1] = *(const bf16x8*)(LDSB(bf) + (wc * 128 + n * 16 + l15) * 128 + offk1); } }

// one A row-pair x all 8 n-frags x K=64 : 32 MFMA
#define MM2(av, p) { \
    _Pragma("unroll") for (int r = 0; r < 2; ++r) \
    _Pragma("unroll") for (int n = 0; n < 8; ++n) { \
        acc[(p)*2+r][n] = __builtin_amdgcn_mfma_f32_16x16x32_bf16( \
            av[r][0], bfr[n][0], acc[(p)*2+r][n], 0, 0, 0); \
        acc[(p)*2+r][n] = __builtin_amdgcn_mfma_f32_16x16x32_bf16( \
            av[r][1], bfr[n][1], acc[(p)*2+r][n], 0, 0, 0); } }

    bf16x8 bfr[8][2], aP[2][2], aQ[2][2];
    f32x4  acc[8][8];
    #pragma unroll
    for (int m = 0; m < 8; ++m)
        #pragma unroll
        for (int n = 0; n < 8; ++n) acc[m][n] = (f32x4)(0.0f);

    // zero-fill slice base: block b owns out[b*16384 .. b*16384+16383]
    f32x4* zbase = zf ? (f32x4*)(zf + (size_t)b * 16384 + tid * 4) : nullptr;
    const f32x4 zero4 = (f32x4)(0.0f);

    // prologue: stage K-tile 0 into buf 0
    STG_A(0, 0); STG_B(0, 0);
    __syncthreads();   // compiler drains vmcnt(0) here

    int cur = 0;
    for (int kt = 0; kt < KTILES; ++kt) {
        // issue next-tile staging first: in flight across this tile's compute
        if (kt + 1 < KTILES) {
            const int nb = cur ^ 1;
            STG_A(nb, kt + 1); STG_B(nb, kt + 1);
        }

        // idle-store-pipe zero-fill: one nontemporal 16B store per K-tile
        if (zbase)
            __builtin_nontemporal_store(zero4, zbase + (size_t)kt * 256);

        // software pipeline: B burst, then A row-pairs read one pair ahead
        RD_B8(cur);
        RD_A2(aP, cur, 0);
        RD_A2(aQ, cur, 1);
        MM2(aP, 0);
        RD_A2(aP, cur, 2);
        MM2(aQ, 1);
        RD_A2(aQ, cur, 3);
        MM2(aP, 2);
        MM2(aQ, 3);

        __syncthreads();   // next buffer staged; all reads of cur done
        cur ^= 1;
    }

    // fold: +b1, relu, *W2 -> per-row partials, then reduce over l15 columns
    float sp[8][4];
    #pragma unroll
    for (int m = 0; m < 8; ++m)
        #pragma unroll
        for (int j = 0; j < 4; ++j) sp[m][j] = 0.0f;
    #pragma unroll
    for (int n = 0; n < 8; ++n)
        #pragma unroll
        for (int m = 0; m < 8; ++m)
            #pragma unroll
            for (int j = 0; j < 4; ++j) {
                float v = acc[m][n][j] + b1v[n];
                v = v > 0.0f ? v : 0.0f;
                sp[m][j] += v * w2v[n];
            }

    #pragma unroll
    for (int m = 0; m < 8; ++m)
        #pragma unroll
        for (int j = 0; j < 4; ++j) {
            float v = sp[m][j];
            v += __shfl_xor(v, 1);
            v += __shfl_xor(v, 2);
            v += __shfl_xor(v, 4);
            v += __shfl_xor(v, 8);
            sp[m][j] = v;
        }

    if (l15 == 0) {
        const size_t base = (size_t)(ht * 2 + wc) * Mc;
        #pragma unroll
        for (int m = 0; m < 8; ++m)
            #pragma unroll
            for (int j = 0; j < 4; ++j) {
                const int row = m0 + wr * 128 + m * 16 + l4 * 4 + j;
                score_part[base + row] = sp[m][j];
            }
    }
}

// -------- Kernel D (fast path): diagonal + attn scatter only ----------------
__global__ void __launch_bounds__(256) finalize_scatter(
    const float* __restrict__ score_part, const float* __restrict__ energy,
    const float* __restrict__ b2, float* __restrict__ out)
{
    const int row = blockIdx.x * 256 + threadIdx.x;       // 0..Mc-1
    float s = b2[0];
    #pragma unroll
    for (int g = 0; g < NSLICE; ++g) s += score_part[(size_t)g * Mc + row];
    const float attn = (1.0f / (1.0f + expf(-s))) * energy[row];
    const int bb = row >> 9;              // batch
    const int n  = row & (Nc - 1);
    out[(size_t)bb * Nc * Nc + (size_t)n * (Nc + 1)] = attn;   // diagonal
    out[(size_t)Bc * Nc * Nc + row] = attn;                    // attn vector
}

// -------- Kernel D (fallback): full filter write (zeros + diag) -------------
__global__ void __launch_bounds__(256) finalize_full(
    const float* __restrict__ score_part, const float* __restrict__ energy,
    const float* __restrict__ b2, float* __restrict__ out)
{
    const int row = blockIdx.x * 2 + (threadIdx.x >> 7);  // 0..Mc-1
    const int t   = threadIdx.x & 127;                    // 128 thr per row

    float s = b2[0];
    #pragma unroll
    for (int g = 0; g < NSLICE; ++g) s += score_part[(size_t)g * Mc + row];
    const float attn = (1.0f / (1.0f + expf(-s))) * energy[row];

    const int n = row & (Nc - 1);
    float4 z = make_float4(0.0f, 0.0f, 0.0f, 0.0f);
    if (t == (n >> 2)) ((float*)&z)[n & 3] = attn;
    ((float4*)(out + (size_t)row * Nc))[t] = z;
    if (t == 0) out[(size_t)Bc * Nc * Nc + row] = attn;
}

// ---------------- Host launcher ---------------------------------------------
extern "C" void kernel_launch(void* const* d_in, const int* in_sizes, int n_in,
                              void* d_out, int out_size, void* d_ws, size_t ws_size,
                              hipStream_t stream) {
    const float* x  = (const float*)d_in[0];
    const float* W1 = (const float*)d_in[1];
    const float* b1 = (const float*)d_in[2];
    const float* W2 = (const float*)d_in[3];
    const float* b2 = (const float*)d_in[4];
    float* out = (float*)d_out;

    const size_t xb_bytes = (size_t)Mc * Dc * 2;     // 64 MB
    const size_t w1_bytes = (size_t)Hc * Dc * 2;     // 4 MB
    const size_t e_bytes  = (size_t)Mc * 4;          // 128 KB
    const size_t s_bytes  = (size_t)NSLICE * Mc * 4; // 2 MB

    char* ws = (char*)d_ws;
    unsigned short* xb;
    bool xb_in_out = false;
    if (ws_size >= xb_bytes + w1_bytes + e_bytes + s_bytes + 256) {
        xb = (unsigned short*)ws; ws += xb_bytes;
    } else {
        // use the filter region of d_out (67 MB >= 64 MB) as bf16-x scratch;
        // finalize_full fully overwrites it afterwards.
        xb = (unsigned short*)d_out;
        xb_in_out = true;
    }
    unsigned short* w1b = (unsigned short*)ws; ws += w1_bytes;
    float* energy = (float*)ws; ws += e_bytes;
    float* score  = (float*)ws; ws += s_bytes;

    const int w1_blocks = (Hc * Dc / 4) / 256;       // 2048
    cast_fused<<<Mc / 8 + w1_blocks, 256, 0, stream>>>(x, W1, xb, w1b, energy);
    fused_gemm_score<<<MTILES * HTILES, 256, 131072, stream>>>(
        xb, w1b, b1, W2, score, xb_in_out ? nullptr : out);
    if (xb_in_out)
        finalize_full<<<Mc / 2, 256, 0, stream>>>(score, energy, b2, out);
    else
        finalize_scatter<<<Mc / 256, 256, 0, stream>>>(score, energy, b2, out);
}

// Round 15
// 151.121 us; speedup vs baseline: 1.1236x; 1.1236x over previous
//
#include <hip/hip_runtime.h>
#include <hip/hip_bf16.h>

// Problem constants (B,N,D,H from reference)
#define Bc 64
#define Nc 512
#define Dc 1024
#define Hc 2048
#define Mc (Bc * Nc)          // 32768 rows

// GEMM tiling: 256x256 tile, BK=64, 8 waves (2M x 4N), double-buffered LDS
#define BM 256
#define BH 256
#define BK 64
#define KTILES (Dc / BK)      // 16
#define MTILES (Mc / BM)      // 128
#define HTILES (Hc / BH)      // 8
#define NSLICE (HTILES * 4)   // 32 score slices (ht x wave-column)

typedef __attribute__((ext_vector_type(8))) short bf16x8;
typedef __attribute__((ext_vector_type(4))) float f32x4;

__device__ __forceinline__ unsigned short f2bf(float f) {
    unsigned u = __float_as_uint(f);
    u += 0x7FFFu + ((u >> 16) & 1u);   // RNE
    return (unsigned short)(u >> 16);
}

__device__ __forceinline__ void stage16(const void* g, void* l) {
    __builtin_amdgcn_global_load_lds(
        (const __attribute__((address_space(1))) unsigned int*)g,
        (__attribute__((address_space(3))) unsigned int*)l,
        16, 0, 0);
}

// ------- Kernel A: fused {cast x + energy (2 rows/wave)} | {cast W1} --------
__global__ void __launch_bounds__(256) cast_fused(
    const float* __restrict__ x, const float* __restrict__ w1,
    unsigned short* __restrict__ xb, unsigned short* __restrict__ w1b,
    float* __restrict__ energy)
{
    const int tid = threadIdx.x;
    if (blockIdx.x < Mc / 8) {
        // 8 rows per block, two rows per wave: 8 independent float4 loads in
        // flight per lane (ILP) before the shfl-reduce tail; no barriers.
        const int row0 = blockIdx.x * 8 + (tid >> 6) * 2;
        const int lane = tid & 63;
        const float4* s0 = (const float4*)(x + (size_t)row0 * Dc);
        const float4* s1 = (const float4*)(x + (size_t)(row0 + 1) * Dc);
        ushort4* d0 = (ushort4*)(xb + (size_t)row0 * Dc);
        ushort4* d1 = (ushort4*)(xb + (size_t)(row0 + 1) * Dc);
        float4 v0[4], v1[4];
        #pragma unroll
        for (int j = 0; j < 4; ++j) v0[j] = s0[lane + j * 64];
        #pragma unroll
        for (int j = 0; j < 4; ++j) v1[j] = s1[lane + j * 64];
        float a = 0.0f, bsum = 0.0f;
        #pragma unroll
        for (int j = 0; j < 4; ++j) {
            ushort4 o;
            o.x = f2bf(v0[j].x); o.y = f2bf(v0[j].y);
            o.z = f2bf(v0[j].z); o.w = f2bf(v0[j].w);
            d0[lane + j * 64] = o;
            a += v0[j].x * v0[j].x + v0[j].y * v0[j].y +
                 v0[j].z * v0[j].z + v0[j].w * v0[j].w;
        }
        #pragma unroll
        for (int j = 0; j < 4; ++j) {
            ushort4 o;
            o.x = f2bf(v1[j].x); o.y = f2bf(v1[j].y);
            o.z = f2bf(v1[j].z); o.w = f2bf(v1[j].w);
            d1[lane + j * 64] = o;
            bsum += v1[j].x * v1[j].x + v1[j].y * v1[j].y +
                    v1[j].z * v1[j].z + v1[j].w * v1[j].w;
        }
        #pragma unroll
        for (int m = 1; m < 64; m <<= 1) {
            a    += __shfl_xor(a, m);
            bsum += __shfl_xor(bsum, m);
        }
        if (lane == 0) {
            energy[row0]     = 1.0f / (1.0f + expf(-a));
            energy[row0 + 1] = 1.0f / (1.0f + expf(-bsum));
        }
    } else {
        const size_t i = (size_t)(blockIdx.x - Mc / 8) * 256 + tid; // x4 elems
        const float4 v = ((const float4*)w1)[i];
        ushort4 o;
        o.x = f2bf(v.x); o.y = f2bf(v.y); o.z = f2bf(v.z); o.w = f2bf(v.w);
        ((ushort4*)w1b)[i] = o;
    }
}

// ---------------- Kernel C: fused bf16 GEMM + relu + W2-reduce --------------
// 256x256 tile per block, 8 waves, double-buffered LDS, prefetch-1 staging
// (R12 core, unchanged: no setprio — it fences the scheduler on lockstep
// schedules; zero-fill on kt>=8 via idle store pipe).
// score_part[(ht*4 + wc)*Mc + row] = sum over slice's 64 h of
//     relu(x.W1[h] + b1[h]) * W2[h]
__global__ void __launch_bounds__(512, 2) fused_gemm_score(
    const unsigned short* __restrict__ xb,    // [Mc][Dc] bf16 bits
    const unsigned short* __restrict__ w1b,   // [Hc][Dc] bf16 bits
    const float* __restrict__ b1,             // [Hc]
    const float* __restrict__ w2,             // [Hc]
    float* __restrict__ score_part,           // [NSLICE][Mc]
    float* __restrict__ zf)                   // filter base to zero, or null
{
    // dynamic LDS: [2 buf][2 mat][256*64] bf16 = 128 KB
    extern __shared__ __attribute__((aligned(16))) unsigned short lds[];

    const int tid  = threadIdx.x;
    const int lane = tid & 63;
    const int wid  = tid >> 6;                // 0..7
    const int wr   = wid >> 2;                // 0..1  (m half: 128 rows)
    const int wc   = wid & 3;                 // 0..3  (h quarter: 64 cols)
    const int l15  = lane & 15;
    const int l4   = lane >> 4;               // 0..3

    // bijective XCD swizzle (1024 % 8 == 0): ht fastest within an XCD so the
    // 8 blocks sharing one x-tile run adjacently; W1 (4MB) stays L2-resident.
    const int b  = blockIdx.x;
    const int wg = (b & 7) * (MTILES * HTILES / 8) + (b >> 3);
    const int mt = wg >> 3;                   // 0..127
    const int ht = wg & 7;                    // 0..7
    const int m0 = mt * BM;
    const int h0 = ht * BH;

    // epilogue coefficients prefetch
    float b1v[4], w2v[4];
    #pragma unroll
    for (int n = 0; n < 4; ++n) {
        const int h = h0 + wc * 64 + n * 16 + l15;
        b1v[n] = b1[h];
        w2v[n] = w2[h];
    }

    // staging geometry (rule #21: linear LDS dest + pre-swizzled src col)
    const int srow    = tid >> 3;             // 0..63
    const int scol_sw = ((((tid & 7) * 16) ^ ((srow & 7) << 4)) >> 1); // elems

    unsigned short* A0p = lds;                // [buf*32768 + mat*16384] elems
    #define LDSBUF(buf, mat) (A0p + (buf) * 32768 + (mat) * 16384)

    // swizzled ds_read byte offsets within a 128-byte row
    const int swz   = (l15 & 7) << 4;
    const int offk0 = ((l4 * 16) ^ swz);
    const int offk1 = ((64 + l4 * 16) ^ swz);
    const int arow  = (wr * 128 + l15) * 128; // byte row base within A
    const int brow  = (wc * 64 + l15) * 128;  // byte row base within B

// fragment reads (8 b128 for an A m-half, 4 b128 for a B n-half)
#define RD_A(dst, bf, mh) { \
    _Pragma("unroll") for (int mf = 0; mf < 4; ++mf) { \
        dst[mf][0] = *(const bf16x8*)((char*)LDSBUF(bf, 0) + arow + ((mh)*64 + mf*16) * 128 + offk0); \
        dst[mf][1] = *(const bf16x8*)((char*)LDSBUF(bf, 0) + arow + ((mh)*64 + mf*16) * 128 + offk1); } }
#define RD_B(dst, bf, nh) { \
    _Pragma("unroll") for (int nf = 0; nf < 2; ++nf) { \
        dst[nf][0] = *(const bf16x8*)((char*)LDSBUF(bf, 1) + brow + ((nh)*32 + nf*16) * 128 + offk0); \
        dst[nf][1] = *(const bf16x8*)((char*)LDSBUF(bf, 1) + brow + ((nh)*32 + nf*16) * 128 + offk1); } }

// one C-quadrant (m-half x n-half) x K=64 : 16 MFMA (no setprio: m190 + R12)
#define MMQ(av, bv, mh, nh) { \
    _Pragma("unroll") for (int mf = 0; mf < 4; ++mf) \
    _Pragma("unroll") for (int nf = 0; nf < 2; ++nf) { \
        acc[(mh)*4+mf][(nh)*2+nf] = __builtin_amdgcn_mfma_f32_16x16x32_bf16( \
            av[mf][0], bv[nf][0], acc[(mh)*4+mf][(nh)*2+nf], 0, 0, 0); \
        acc[(mh)*4+mf][(nh)*2+nf] = __builtin_amdgcn_mfma_f32_16x16x32_bf16( \
            av[mf][1], bv[nf][1], acc[(mh)*4+mf][(nh)*2+nf], 0, 0, 0); } }

    f32x4 acc[8][4];
    #pragma unroll
    for (int m = 0; m < 8; ++m)
        #pragma unroll
        for (int n = 0; n < 4; ++n) acc[m][n] = (f32x4)(0.0f);

    // zero-fill slice base: block b owns out[b*16384 .. b*16384+16383]
    f32x4* zbase = zf ? (f32x4*)(zf + (size_t)b * 16384 + tid * 4) : nullptr;
    const f32x4 zero4 = (f32x4)(0.0f);

    // prologue: stage K-tile 0 into buf 0
    #pragma unroll
    for (int c = 0; c < 4; ++c) {
        stage16(xb  + (size_t)(m0 + c * 64 + srow) * Dc + scol_sw,
                ((char*)LDSBUF(0, 0)) + c * 8192 + tid * 16);
        stage16(w1b + (size_t)(h0 + c * 64 + srow) * Dc + scol_sw,
                ((char*)LDSBUF(0, 1)) + c * 8192 + tid * 16);
    }
    __syncthreads();   // compiler drains vmcnt(0) here

    int cur = 0;
    for (int kt = 0; kt < KTILES; ++kt) {
        // issue next-tile staging first: in flight across this tile's compute
        if (kt + 1 < KTILES) {
            const int k0 = (kt + 1) * BK;
            const int nb = cur ^ 1;
            #pragma unroll
            for (int c = 0; c < 4; ++c) {
                stage16(xb  + (size_t)(m0 + c * 64 + srow) * Dc + k0 + scol_sw,
                        ((char*)LDSBUF(nb, 0)) + c * 8192 + tid * 16);
                stage16(w1b + (size_t)(h0 + c * 64 + srow) * Dc + k0 + scol_sw,
                        ((char*)LDSBUF(nb, 1)) + c * 8192 + tid * 16);
            }
        }

        // idle-store-pipe zero-fill: one nontemporal 16B store on kt=8..15
        if (zbase && kt >= 8)
            __builtin_nontemporal_store(zero4, zbase + (size_t)(kt - 8) * 512);

        bf16x8 a0[4][2], a1[4][2], b0[2][2], b1f[2][2];

        // software pipeline: reads for quadrant q+1 issued BEFORE MFMA(q)
        RD_A(a0, cur, 0); RD_B(b0, cur, 0);   // q0 operands (8-read burst)
        RD_B(b1f, cur, 1);                    // q1 operand, under MM(q0)
        MMQ(a0, b0, 0, 0);
        RD_A(a1, cur, 1);                     // q2 operand, under MM(q1)
        MMQ(a0, b1f, 0, 1);
        MMQ(a1, b1f, 1, 1);
        MMQ(a1, b0, 1, 0);

        __syncthreads();   // next buffer staged; all reads of cur done
        cur ^= 1;
    }

    // fold: +b1, relu, *W2 -> per-row partials, then reduce over l15 columns
    float sp[8][4];
    #pragma unroll
    for (int m = 0; m < 8; ++m)
        #pragma unroll
        for (int j = 0; j < 4; ++j) sp[m][j] = 0.0f;
    #pragma unroll
    for (int n = 0; n < 4; ++n)
        #pragma unroll
        for (int m = 0; m < 8; ++m)
            #pragma unroll
            for (int j = 0; j < 4; ++j) {
                float v = acc[m][n][j] + b1v[n];
                v = v > 0.0f ? v : 0.0f;
                sp[m][j] += v * w2v[n];
            }

    #pragma unroll
    for (int m = 0; m < 8; ++m)
        #pragma unroll
        for (int j = 0; j < 4; ++j) {
            float v = sp[m][j];
            v += __shfl_xor(v, 1);
            v += __shfl_xor(v, 2);
            v += __shfl_xor(v, 4);
            v += __shfl_xor(v, 8);
            sp[m][j] = v;
        }

    if (l15 == 0) {
        const size_t base = (size_t)(ht * 4 + wc) * Mc;
        #pragma unroll
        for (int m = 0; m < 8; ++m)
            #pragma unroll
            for (int j = 0; j < 4; ++j) {
                const int row = m0 + wr * 128 + m * 16 + l4 * 4 + j;
                score_part[base + row] = sp[m][j];
            }
    }
}

// -------- Kernel D (fast path): diagonal + attn scatter only ----------------
__global__ void __launch_bounds__(256) finalize_scatter(
    const float* __restrict__ score_part, const float* __restrict__ energy,
    const float* __restrict__ b2, float* __restrict__ out)
{
    const int row = blockIdx.x * 256 + threadIdx.x;       // 0..Mc-1
    float s = b2[0];
    #pragma unroll
    for (int g = 0; g < NSLICE; ++g) s += score_part[(size_t)g * Mc + row];
    const float attn = (1.0f / (1.0f + expf(-s))) * energy[row];
    const int bb = row >> 9;              // batch
    const int n  = row & (Nc - 1);
    out[(size_t)bb * Nc * Nc + (size_t)n * (Nc + 1)] = attn;   // diagonal
    out[(size_t)Bc * Nc * Nc + row] = attn;                    // attn vector
}

// -------- Kernel D (fallback): full filter write (zeros + diag) -------------
__global__ void __launch_bounds__(256) finalize_full(
    const float* __restrict__ score_part, const float* __restrict__ energy,
    const float* __restrict__ b2, float* __restrict__ out)
{
    const int row = blockIdx.x * 2 + (threadIdx.x >> 7);  // 0..Mc-1
    const int t   = threadIdx.x & 127;                    // 128 thr per row

    float s = b2[0];
    #pragma unroll
    for (int g = 0; g < NSLICE; ++g) s += score_part[(size_t)g * Mc + row];
    const float attn = (1.0f / (1.0f + expf(-s))) * energy[row];

    const int n = row & (Nc - 1);
    float4 z = make_float4(0.0f, 0.0f, 0.0f, 0.0f);
    if (t == (n >> 2)) ((float*)&z)[n & 3] = attn;
    ((float4*)(out + (size_t)row * Nc))[t] = z;
    if (t == 0) out[(size_t)Bc * Nc * Nc + row] = attn;
}

// ---------------- Host launcher ---------------------------------------------
extern "C" void kernel_launch(void* const* d_in, const int* in_sizes, int n_in,
                              void* d_out, int out_size, void* d_ws, size_t ws_size,
                              hipStream_t stream) {
    const float* x  = (const float*)d_in[0];
    const float* W1 = (const float*)d_in[1];
    const float* b1 = (const float*)d_in[2];
    const float* W2 = (const float*)d_in[3];
    const float* b2 = (const float*)d_in[4];
    float* out = (float*)d_out;

    const size_t xb_bytes = (size_t)Mc * Dc * 2;     // 64 MB
    const size_t w1_bytes = (size_t)Hc * Dc * 2;     // 4 MB
    const size_t e_bytes  = (size_t)Mc * 4;          // 128 KB
    const size_t s_bytes  = (size_t)NSLICE * Mc * 4; // 4 MB

    char* ws = (char*)d_ws;
    unsigned short* xb;
    bool xb_in_out = false;
    if (ws_size >= xb_bytes + w1_bytes + e_bytes + s_bytes + 256) {
        xb = (unsigned short*)ws; ws += xb_bytes;
    } else {
        // use the filter region of d_out (67 MB >= 64 MB) as bf16-x scratch;
        // finalize_full fully overwrites it afterwards.
        xb = (unsigned short*)d_out;
        xb_in_out = true;
    }
    unsigned short* w1b = (unsigned short*)ws; ws += w1_bytes;
    float* energy = (float*)ws; ws += e_bytes;
    float* score  = (float*)ws; ws += s_bytes;

    const int w1_blocks = (Hc * Dc / 4) / 256;       // 2048
    cast_fused<<<Mc / 8 + w1_blocks, 256, 0, stream>>>(x, W1, xb, w1b, energy);
    fused_gemm_score<<<MTILES * HTILES, 512, 131072, stream>>>(
        xb, w1b, b1, W2, score, xb_in_out ? nullptr : out);
    if (xb_in_out)
        finalize_full<<<Mc / 2, 256, 0, stream>>>(score, energy, b2, out);
    else
        finalize_scatter<<<Mc / 256, 256, 0, stream>>>(score, energy, b2, out);
}